// Round 3
// baseline (260.692 us; speedup 1.0000x reference)
//
#include <hip/hip_runtime.h>

#define WIDTH  1024
#define HEIGHT 1024
#define ROWS_PER_BLOCK 8

__global__ __launch_bounds__(256) void fdtd_kernel(
    const float* __restrict__ u1,
    const float* __restrict__ u0,
    const float* __restrict__ j2,
    const float* __restrict__ j0,
    float* __restrict__ out)
{
    const int row0 = blockIdx.x * ROWS_PER_BLOCK;   // first global row (B*H space)
    const int y0   = row0 & (HEIGHT - 1);           // y within image; ROWS_PER_BLOCK | HEIGHT
    const int lane = threadIdx.x & 63;
    const int x0   = threadIdx.x << 2;              // 4 floats per thread
    long base = (long)row0 * WIDTH + x0;

    const float4 zero = make_float4(0.f, 0.f, 0.f, 0.f);

    // register window of u1: up / c march down the rows
    float4 up = (y0 > 0) ? *(const float4*)(u1 + base - WIDTH) : zero;
    float4 c  = *(const float4*)(u1 + base);

#pragma unroll
    for (int r = 0; r < ROWS_PER_BLOCK; ++r) {
        const int y = y0 + r;
        const float4 dn = (y < HEIGHT - 1) ? *(const float4*)(u1 + base + WIDTH) : zero;
        const float4 a0 = *(const float4*)(u0 + base);
        const float4 b2 = *(const float4*)(j2 + base);
        const float4 b0 = *(const float4*)(j0 + base);

        // x-neighbors: in-register via wave shuffle; wave boundary via scalar load
        float left  = __shfl_up(c.w, 1);
        float right = __shfl_down(c.x, 1);
        if (lane == 0)  left  = (x0 > 0)         ? u1[base - 1] : 0.0f;
        if (lane == 63) right = (x0 + 4 < WIDTH) ? u1[base + 4] : 0.0f;

        float4 o;
        o.x = 2.0f * c.x - a0.x + 0.25f * (up.x + dn.x + left + c.y - 4.0f * c.x) - 0.0025f * (b2.x - b0.x);
        o.y = 2.0f * c.y - a0.y + 0.25f * (up.y + dn.y + c.x  + c.z - 4.0f * c.y) - 0.0025f * (b2.y - b0.y);
        o.z = 2.0f * c.z - a0.z + 0.25f * (up.z + dn.z + c.y  + c.w - 4.0f * c.z) - 0.0025f * (b2.z - b0.z);
        o.w = 2.0f * c.w - a0.w + 0.25f * (up.w + dn.w + c.z  + right - 4.0f * c.w) - 0.0025f * (b2.w - b0.w);
        *(float4*)(out + base) = o;

        up = c;
        c  = dn;
        base += WIDTH;
    }
}

extern "C" void kernel_launch(void* const* d_in, const int* in_sizes, int n_in,
                              void* d_out, int out_size, void* d_ws, size_t ws_size,
                              hipStream_t stream) {
    const float* u1 = (const float*)d_in[0];
    const float* u0 = (const float*)d_in[1];
    const float* j2 = (const float*)d_in[2];
    const float* j0 = (const float*)d_in[3];
    float* out = (float*)d_out;

    const int nrows = out_size / WIDTH;                 // B*H = 16384
    dim3 block(WIDTH / 4);                              // 256 threads
    dim3 grid(nrows / ROWS_PER_BLOCK);                  // 2048 blocks
    fdtd_kernel<<<grid, block, 0, stream>>>(u1, u0, j2, j0, out);
}

// Round 5
// 246.407 us; speedup vs baseline: 1.0580x; 1.0580x over previous
//
#include <hip/hip_runtime.h>

#define WIDTH  1024
#define HEIGHT 1024

typedef float vfloat4 __attribute__((ext_vector_type(4)));

__global__ __launch_bounds__(256) void fdtd_kernel(
    const float* __restrict__ u1,
    const float* __restrict__ u0,
    const float* __restrict__ j2,
    const float* __restrict__ j0,
    float* __restrict__ out,
    int rowsplit)                               // nrows/2; row2 = row1 + rowsplit
{
    const int row = blockIdx.x;                 // 0 .. rowsplit-1
    const int y   = row & (HEIGHT - 1);         // same y for both tiles (rowsplit % HEIGHT == 0)
    const int x0  = threadIdx.x << 2;           // 4 floats per thread
    const vfloat4 zero = {0.f, 0.f, 0.f, 0.f};

    long base[2];
    base[0] = (long)row * WIDTH + x0;
    base[1] = base[0] + (long)rowsplit * WIDTH;

    // ---- issue ALL loads up front (12 x 16B vector + 4 scalar edge) ----
    vfloat4 c[2], up[2], dn[2], a0[2], v2[2], v0[2];
    float   lf[2], rt[2];
#pragma unroll
    for (int k = 0; k < 2; ++k) {
        const long b = base[k];
        c[k]  = *(const vfloat4*)(u1 + b);
        up[k] = (y > 0)          ? *(const vfloat4*)(u1 + b - WIDTH) : zero;
        dn[k] = (y < HEIGHT - 1) ? *(const vfloat4*)(u1 + b + WIDTH) : zero;
        a0[k] = __builtin_nontemporal_load((const vfloat4*)(u0 + b));
        v2[k] = __builtin_nontemporal_load((const vfloat4*)(j2 + b));
        v0[k] = __builtin_nontemporal_load((const vfloat4*)(j0 + b));
        lf[k] = (x0 > 0)         ? u1[b - 1] : 0.0f;
        rt[k] = (x0 + 4 < WIDTH) ? u1[b + 4] : 0.0f;
    }

    // ---- compute + store both tiles ----
#pragma unroll
    for (int k = 0; k < 2; ++k) {
        vfloat4 o;
        o.x = 2.0f * c[k].x - a0[k].x + 0.25f * (up[k].x + dn[k].x + lf[k]   + c[k].y - 4.0f * c[k].x)
            - 0.0025f * (v2[k].x - v0[k].x);
        o.y = 2.0f * c[k].y - a0[k].y + 0.25f * (up[k].y + dn[k].y + c[k].x  + c[k].z - 4.0f * c[k].y)
            - 0.0025f * (v2[k].y - v0[k].y);
        o.z = 2.0f * c[k].z - a0[k].z + 0.25f * (up[k].z + dn[k].z + c[k].y  + c[k].w - 4.0f * c[k].z)
            - 0.0025f * (v2[k].z - v0[k].z);
        o.w = 2.0f * c[k].w - a0[k].w + 0.25f * (up[k].w + dn[k].w + c[k].z  + rt[k]  - 4.0f * c[k].w)
            - 0.0025f * (v2[k].w - v0[k].w);
        __builtin_nontemporal_store(o, (vfloat4*)(out + base[k]));
    }
}

extern "C" void kernel_launch(void* const* d_in, const int* in_sizes, int n_in,
                              void* d_out, int out_size, void* d_ws, size_t ws_size,
                              hipStream_t stream) {
    const float* u1 = (const float*)d_in[0];
    const float* u0 = (const float*)d_in[1];
    const float* j2 = (const float*)d_in[2];
    const float* j0 = (const float*)d_in[3];
    float* out = (float*)d_out;

    const int nrows = out_size / WIDTH;         // B*H = 16384
    const int rowsplit = nrows / 2;             // 8192
    dim3 block(WIDTH / 4);                      // 256 threads, one row-pair per block
    dim3 grid(rowsplit);                        // 8192 blocks
    fdtd_kernel<<<grid, block, 0, stream>>>(u1, u0, j2, j0, out, rowsplit);
}